// Round 5
// baseline (331.073 us; speedup 1.0000x reference)
//
#include <hip/hip_runtime.h>

// Head_13: fused single-head causal attention, B=1024 T=128 C=384 HS=64, fp32 I/O.
// R5: two-kernel split at the phase boundary for per-phase rocprof visibility.
//  - qkv_kernel: R4's phase 1 (LDS-staged x via global_load_lds) + epilogue,
//    then repack q/k/v to GLOBAL ws in fragment-major bf16 (per-lane 16B entries).
//  - attn2_kernel: barrier-free attention; q/k/v read as direct coalesced 16B
//    fragment loads from ws; only P bounces through (wave-private) LDS.

typedef __attribute__((ext_vector_type(8)))  short  short8;   // 8 bf16 = 4 VGPR
typedef __attribute__((ext_vector_type(16))) float  floatx16; // MFMA 32x32 acc
typedef __attribute__((ext_vector_type(4)))  float  float4v;

#define T_DIM   128
#define C_DIM   384
#define HS      64
#define NCHUNK  12            // 384/32
#define SLAB    1536          // shorts per (c,ks,half) W slab = 192 n * 8 k

#define QK_PITCH 68           // 64+4 bf16 -> 136 B row
#define V_PITCH  132          // 128+4 bf16 -> 264 B
#define P_PITCH  132
#define Q_OFF  0
#define K_OFF  17408          // 128*136
#define XV_OFF 34816          // x-stage tile (16 KB) in phase 1; V (16.9 KB) afterwards
#define LDS_A  51712          // 3 blocks/CU
#define LDS_B  33792          // P: 128*264 -> 4 blocks/CU by LDS

// ws layout: wt fragments (147456 B), then qkv fragment-major bf16:
// per batch 24576 shorts: q[1024 e]*8, k[+8192], v[+16384]
#define QKV_OFF_SHORTS 73728
#define QKV_PER_B      24576

#define MFMA(a,b,c) __builtin_amdgcn_mfma_f32_32x32x16_bf16((a),(b),(c),0,0,0)

__device__ inline unsigned short f2bf(float f){ // fp32 -> bf16 RTNE
    unsigned u = __builtin_bit_cast(unsigned, f);
    u += 0x7FFFu + ((u >> 16) & 1u);
    return (unsigned short)(u >> 16);
}

__device__ inline short8 ld_b64x2(const char* p){ // 16B fragment via two 8B LDS reads
    union { unsigned long long u[2]; short8 s; } r;
    r.u[0] = *(const unsigned long long*)(p);
    r.u[1] = *(const unsigned long long*)(p + 8);
    return r.s;
}

// W[q|k|v] fp32 [384][64] -> wt bf16 fragment-major: [c][ks][half][n=192][j=8]
__global__ void prep_wt(const float* __restrict__ Wq, const float* __restrict__ Wk,
                        const float* __restrict__ Wv, unsigned short* __restrict__ wt){
    int idx = blockIdx.x * 256 + threadIdx.x;
    if (idx >= 48 * SLAB) return;
    int slab = idx / SLAB;
    int rem  = idx - slab * SLAB;
    int n = rem >> 3, j = rem & 7;
    int half = slab & 1, ks = (slab >> 1) & 1, c = slab >> 2;
    int kg = c*32 + ks*16 + half*8 + j;
    const float* W = (n < 64) ? Wq : (n < 128) ? Wk : Wv;
    wt[idx] = f2bf(W[kg * HS + (n & 63)]);
}

__launch_bounds__(256, 3)
__global__ void qkv_kernel(const float* __restrict__ x,
                           const unsigned short* __restrict__ wtg,
                           unsigned short* __restrict__ qkvg){
    __shared__ __align__(16) char smem[LDS_A];
    const int tid  = threadIdx.x;
    const int lane = tid & 63;
    const int wave = tid >> 6;
    const int l31  = lane & 31;
    const int half = lane >> 5;
    const int b    = blockIdx.x;
    const char* xb = (const char*)(x + (size_t)b * (T_DIM * C_DIM));

    const short8* wf = (const short8*)wtg;
    floatx16 acc[6] = {};                 // one per N-block (cols 32*nbl + l31)

    const char* gsrc[4];
    #pragma unroll
    for (int i = 0; i < 4; ++i){
        int o  = wave*1024 + i*4096 + lane*16;
        int t  = o >> 7;
        int pp = ((o >> 4) & 7) ^ (t & 7);
        gsrc[i] = xb + t*1536 + pp*16;
    }
    const int xrow_base = XV_OFF + (32*wave + l31) * 128;
    const int rs = (32*wave + l31) & 7;

    for (int c = 0; c < NCHUNK; ++c){
        __syncthreads();
        #pragma unroll
        for (int i = 0; i < 4; ++i){
            __builtin_amdgcn_global_load_lds(
                (const __attribute__((address_space(1))) void*)(gsrc[i] + c*128),
                (__attribute__((address_space(3))) void*)(smem + XV_OFF + wave*1024 + i*4096),
                16, 0, 0);
        }
        __syncthreads();

        short8 afrag[2];
        #pragma unroll
        for (int ks = 0; ks < 2; ++ks){
            int q0 = ks*4 + half*2;
            float4v lo = *(const float4v*)(smem + xrow_base + ((q0  ) ^ rs)*16);
            float4v hi = *(const float4v*)(smem + xrow_base + ((q0+1) ^ rs)*16);
            short8 a;
            a[0]=(short)f2bf(lo[0]); a[1]=(short)f2bf(lo[1]);
            a[2]=(short)f2bf(lo[2]); a[3]=(short)f2bf(lo[3]);
            a[4]=(short)f2bf(hi[0]); a[5]=(short)f2bf(hi[1]);
            a[6]=(short)f2bf(hi[2]); a[7]=(short)f2bf(hi[3]);
            afrag[ks] = a;
        }
        #pragma unroll
        for (int ks = 0; ks < 2; ++ks){
            const short8* slab = wf + ((c*2 + ks)*2 + half) * 192;
            #pragma unroll
            for (int nbl = 0; nbl < 6; ++nbl){
                short8 bfrag = slab[32*nbl + l31];
                acc[nbl] = MFMA(afrag[ks], bfrag, acc[nbl]);
            }
        }
    }
    __syncthreads();   // x tile dead; V overlays it

    // epilogue: q,k row-major (scale*log2e folded into q), v [h][t] -> LDS
    const float QSCALE = 0.125f * 1.44269504088896f;
    #pragma unroll
    for (int nb = 0; nb < 6; ++nb){
        floatx16 A = acc[nb];
        if (nb < 4){
            int base  = (nb < 2) ? Q_OFF : K_OFF;
            int col   = 32 * (nb & 1) + l31;
            float sc  = (nb < 2) ? QSCALE : 1.0f;
            char* bp  = smem + base + col * 2;
            #pragma unroll
            for (int r = 0; r < 16; ++r){
                int t = 32*wave + (r&3) + 8*(r>>2) + 4*half;
                *(unsigned short*)(bp + t * (QK_PITCH*2)) = f2bf(A[r] * sc);
            }
        } else {
            int h = 32*(nb-4) + l31;
            char* bp = smem + XV_OFF + h * (V_PITCH*2);
            #pragma unroll
            for (int g = 0; g < 4; ++g){
                int t0 = 32*wave + 8*g + 4*half;
                union { unsigned short s[4]; unsigned long long u; } pk;
                pk.s[0]=f2bf(A[4*g+0]); pk.s[1]=f2bf(A[4*g+1]);
                pk.s[2]=f2bf(A[4*g+2]); pk.s[3]=f2bf(A[4*g+3]);
                *(unsigned long long*)(bp + t0*2) = pk.u;
            }
        }
    }
    __syncthreads();

    // repack LDS -> global fragment-major bf16 (coalesced 16B/lane stores)
    unsigned short* qkv = qkvg + (size_t)b * QKV_PER_B;
    #pragma unroll
    for (int i = 0; i < 4; ++i){           // Q: e = (ks*2+half)*128 + t
        int e = tid + 256*i;
        int t = e & 127, kh = e >> 7;
        const char* src = smem + Q_OFF + t*(QK_PITCH*2) + kh*16;
        union { unsigned long long u[2]; float4v v; } r;
        r.u[0] = *(const unsigned long long*)src;
        r.u[1] = *(const unsigned long long*)(src + 8);
        *(float4v*)(qkv + e*8) = r.v;
    }
    #pragma unroll
    for (int i = 0; i < 4; ++i){           // K
        int e = tid + 256*i;
        int t = e & 127, kh = e >> 7;
        const char* src = smem + K_OFF + t*(QK_PITCH*2) + kh*16;
        union { unsigned long long u[2]; float4v v; } r;
        r.u[0] = *(const unsigned long long*)src;
        r.u[1] = *(const unsigned long long*)(src + 8);
        *(float4v*)(qkv + 8192 + e*8) = r.v;
    }
    #pragma unroll
    for (int i = 0; i < 4; ++i){           // V: e = (ks*2+half)*64 + h ; 16B = t-run
        int e = tid + 256*i;
        int h = e & 63, kh = e >> 6;
        const char* src = smem + XV_OFF + h*(V_PITCH*2) + kh*16;
        union { unsigned long long u[2]; float4v v; } r;
        r.u[0] = *(const unsigned long long*)src;
        r.u[1] = *(const unsigned long long*)(src + 8);
        *(float4v*)(qkv + 16384 + e*8) = r.v;
    }
}

__launch_bounds__(256, 3)
__global__ void attn2_kernel(const unsigned short* __restrict__ qkvg,
                             float* __restrict__ out){
    __shared__ __align__(16) char smem[LDS_B];   // P only; wave-private rows
    const int tid  = threadIdx.x;
    const int lane = tid & 63;
    const int wave = tid >> 6;
    const int l31  = lane & 31;
    const int half = lane >> 5;
    const int koff = half * 8;
    const int b    = blockIdx.x;
    const short8* qf = (const short8*)(qkvg + (size_t)b * QKV_PER_B);
    const short8* kf = qf + 1024;
    const short8* vf = qf + 2048;

    // S = q k^T (causal tiles only)
    floatx16 accS[4] = {};
    #pragma unroll
    for (int ks = 0; ks < 4; ++ks){
        short8 aq = qf[(ks*2+half)*128 + 32*wave + l31];
        #pragma unroll
        for (int st = 0; st < 4; ++st)
            if (st <= wave){
                short8 bk = kf[(ks*2+half)*128 + 32*st + l31];
                accS[st] = MFMA(aq, bk, accS[st]);
            }
    }
    // P = exp2(S) (scale folded upstream), causal mask on diagonal tile
    #pragma unroll
    for (int st = 0; st < 4; ++st)
        if (st <= wave){
            #pragma unroll
            for (int r = 0; r < 16; ++r){
                int trow = (r&3) + 8*(r>>2) + 4*half;
                float e = exp2f(accS[st][r]);
                if (st == wave && l31 > trow) e = 0.0f;
                accS[st][r] = e;
            }
        }

    // rowsum -> 1/l (butterfly within 32-lane half; accS[st>wave] are zero)
    float linv[16];
    #pragma unroll
    for (int r = 0; r < 16; ++r){
        float l = accS[0][r] + accS[1][r] + accS[2][r] + accS[3][r];
        #pragma unroll
        for (int m = 1; m <= 16; m <<= 1)
            l += __shfl_xor(l, m);
        linv[r] = 1.0f / l;
    }

    // P -> LDS (A-layout); rows 32w..32w+31 are wave-private -> no barrier
    #pragma unroll
    for (int st = 0; st < 4; ++st)
        if (st <= wave){
            char* bp = smem + (32*st + l31) * 2;
            #pragma unroll
            for (int r = 0; r < 16; ++r){
                int t = 32*wave + (r&3) + 8*(r>>2) + 4*half;
                *(unsigned short*)(bp + t * (P_PITCH*2)) = f2bf(accS[st][r]);
            }
        }

    floatx16 accO0 = {}, accO1 = {};
    const int nks = 2 * (wave + 1);
    #pragma unroll
    for (int ks = 0; ks < 8; ++ks)
        if (ks < nks){
            short8 ap  = ld_b64x2(smem + (32*wave + l31)*(P_PITCH*2) + (ks*16 + koff)*2);
            short8 bv0 = vf[(ks*2+half)*64 + l31];
            short8 bv1 = vf[(ks*2+half)*64 + l31 + 32];
            accO0 = MFMA(ap, bv0, accO0);
            accO1 = MFMA(ap, bv1, accO1);
        }

    float* ob = out + (size_t)b * (T_DIM * HS);
    #pragma unroll
    for (int r = 0; r < 16; ++r){
        int t = 32*wave + (r&3) + 8*(r>>2) + 4*half;
        ob[t*HS + l31]      = accO0[r] * linv[r];
        ob[t*HS + l31 + 32] = accO1[r] * linv[r];
    }
}

extern "C" void kernel_launch(void* const* d_in, const int* in_sizes, int n_in,
                              void* d_out, int out_size, void* d_ws, size_t ws_size,
                              hipStream_t stream){
    const float* x  = (const float*)d_in[0];
    const float* Wq = (const float*)d_in[1];
    const float* Wk = (const float*)d_in[2];
    const float* Wv = (const float*)d_in[3];
    unsigned short* wt   = (unsigned short*)d_ws;            // 147456 B
    unsigned short* qkvg = wt + QKV_OFF_SHORTS;              // 50.3 MB

    prep_wt<<<288, 256, 0, stream>>>(Wq, Wk, Wv, wt);
    qkv_kernel<<<1024, 256, 0, stream>>>(x, wt, qkvg);
    attn2_kernel<<<1024, 256, 0, stream>>>(qkvg, (float*)d_out);
}